// Round 1
// baseline (504.809 us; speedup 1.0000x reference)
//
#include <hip/hip_runtime.h>
#include <math.h>

#define BN 4
#define DD 256
#define LL 4096
#define NS 16
#define NCH 128  // scan chunks
#define CT 32    // chunk length (NCH*CT == LL)
#define LOG2E 1.4426950408889634f

typedef __bf16 bf16x8 __attribute__((ext_vector_type(8)));
typedef float f32x4 __attribute__((ext_vector_type(4)));

__device__ __forceinline__ float softplus_f(float v) {
  return v > 20.f ? v : log1pf(__expf(v));
}
__device__ __forceinline__ float silu_f(float v) {
  return v / (1.f + __expf(-v));
}

// ---------------- K1: MFMA bf16 GEMM with inline f32->bf16 conversion ----------------
__global__ __launch_bounds__(256) void k1_mfma(
    const float* __restrict__ W, const float* __restrict__ u,
    float* __restrict__ xpre, float* __restrict__ zb) {
  __shared__ float Af[128 * 36];   // [e][k] f32, stride 36
  __shared__ float Bf[32 * 68];    // [k][l] f32, stride 68
  const int l0 = blockIdx.x * 64;
  const int e0 = blockIdx.y * 128;
  const int b  = blockIdx.z;
  const int tid = threadIdx.x;
  const int lane = tid & 63, w = tid >> 6;
  const int m16 = lane & 15, quad = lane >> 4;

  f32x4 acc[2][4];
#pragma unroll
  for (int i = 0; i < 2; ++i)
#pragma unroll
    for (int j = 0; j < 4; ++j) acc[i][j] = (f32x4){0.f, 0.f, 0.f, 0.f};

  const float* Ub = u + (size_t)b * DD * LL;

  for (int k0 = 0; k0 < DD; k0 += 32) {
    if (k0) __syncthreads();
#pragma unroll
    for (int it = 0; it < 4; ++it) {
      int f4 = tid + it * 256;
      int e = f4 >> 3, kq = f4 & 7;
      *(float4*)&Af[e * 36 + kq * 4] =
          *(const float4*)(W + (size_t)(e0 + e) * DD + k0 + kq * 4);
    }
#pragma unroll
    for (int it = 0; it < 2; ++it) {
      int f4 = tid + it * 256;
      int kk = f4 >> 4, lq = f4 & 15;
      *(float4*)&Bf[kk * 68 + lq * 4] =
          *(const float4*)(Ub + (size_t)(k0 + kk) * LL + l0 + lq * 4);
    }
    __syncthreads();
    bf16x8 afr[2], bfr[4];
#pragma unroll
    for (int te = 0; te < 2; ++te) {
      const float* src = &Af[(w * 32 + te * 16 + m16) * 36 + quad * 8];
      bf16x8 t;
#pragma unroll
      for (int j = 0; j < 8; ++j) t[j] = (__bf16)src[j];
      afr[te] = t;
    }
#pragma unroll
    for (int tl = 0; tl < 4; ++tl) {
      bf16x8 t;
#pragma unroll
      for (int j = 0; j < 8; ++j) t[j] = (__bf16)Bf[(quad * 8 + j) * 68 + tl * 16 + m16];
      bfr[tl] = t;
    }
#pragma unroll
    for (int te = 0; te < 2; ++te)
#pragma unroll
      for (int tl = 0; tl < 4; ++tl)
        acc[te][tl] = __builtin_amdgcn_mfma_f32_16x16x32_bf16(afr[te], bfr[tl], acc[te][tl], 0, 0, 0);
  }

#pragma unroll
  for (int te = 0; te < 2; ++te) {
#pragma unroll
    for (int tl = 0; tl < 4; ++tl) {
      int col = l0 + tl * 16 + m16;
#pragma unroll
      for (int r = 0; r < 4; ++r) {
        int e = e0 + w * 32 + te * 16 + quad * 4 + r;
        float v = acc[te][tl][r];
        if (e < DD) xpre[((size_t)b * DD + e) * LL + col] = v;
        else        zb[((size_t)b * DD + (e - DD)) * LL + col] = v;
      }
    }
  }
}

// ---------------- K2: depthwise conv == 3-tap along d, weights per l ----------------
__global__ __launch_bounds__(256) void k2_conv(
    const float* __restrict__ xpre, const float* __restrict__ cw,
    const float* __restrict__ cb, float* __restrict__ xo) {
  const int bd = blockIdx.x;       // b*256 + d
  const int d = bd & 255;
  const size_t row = (size_t)bd * LL;
  const float* r1 = xpre + row;
  const bool has0 = d > 0, has2 = d < DD - 1;
  for (int j = threadIdx.x; j < LL; j += 256) {
    float w0 = cw[j * 9 + 3], w1 = cw[j * 9 + 4], w2 = cw[j * 9 + 5];
    float v = cb[j] + r1[j] * w1;
    if (has0) v += r1[j - LL] * w0;
    if (has2) v += r1[j + LL] * w2;
    xo[row + j] = v;
  }
}

// ---------------- K3: x_proj GEMM, 6 rows/block, no LDS / no barriers ----------
__global__ __launch_bounds__(256) void k3_xproj(
    const float* __restrict__ xc,
    const float* __restrict__ xpw, const float* __restrict__ xpwB,
    float* __restrict__ dtr, float* __restrict__ gB, float* __restrict__ gC) {
  const int tid = threadIdx.x;
  const int l   = blockIdx.x * 256 + tid;
  const int b   = blockIdx.y;
  const int zz  = blockIdx.z;            // dir*8 + rg
  const int dir = zz >> 3, rg = zz & 7;
  const int rbase = rg * 6;
  const float* W = (dir ? xpwB : xpw) + (size_t)rbase * DD;   // 6 rows x 256
  const float* xcol = xc + (size_t)b * DD * LL + l;

  float acc[6] = {0.f, 0.f, 0.f, 0.f, 0.f, 0.f};

#pragma unroll 8
  for (int d = 0; d < DD; ++d) {
    float xv = xcol[(size_t)d * LL];
#pragma unroll
    for (int i = 0; i < 6; ++i) acc[i] += W[i * DD + d] * xv;
  }

  const size_t ob = ((size_t)dir * BN + b);
#pragma unroll
  for (int i = 0; i < 6; ++i) {
    int r = rbase + i;
    if (r < 16)
      dtr[(ob * 16 + r) * LL + l] = acc[i];
    else if (r < 32)
      gB[(ob * NS + (r - 16)) * LL + l] = acc[i];
    else
      gC[(ob * NS + (r - 32)) * LL + l] = acc[i];
  }
}

// ---------------- K3b: dt_proj + softplus -> gdelta; dtr register-cached ----------
__global__ __launch_bounds__(256) void k3b_dtproj(
    const float* __restrict__ dtr,
    const float* __restrict__ dtw, const float* __restrict__ dtwB,
    const float* __restrict__ dtb,
    float* __restrict__ gdelta) {
  const int tid = threadIdx.x;
  const int l   = blockIdx.x * 256 + tid;
  const int b   = blockIdx.y & 3;
  const int dir = blockIdx.y >> 2;
  const int d0  = blockIdx.z * 64;
  const size_t ob = ((size_t)dir * BN + b);
  const float* dw = (dir ? dtwB : dtw);

  float tr[16];
#pragma unroll
  for (int r = 0; r < 16; ++r) tr[r] = dtr[(ob * 16 + r) * LL + l];

#pragma unroll 4
  for (int d = d0; d < d0 + 64; ++d) {
    float acc = dtb[d];
#pragma unroll
    for (int r = 0; r < 16; ++r) acc += dw[d * 16 + r] * tr[r];
    gdelta[(ob * DD + d) * LL + l] = softplus_f(acc);
  }
}

// ---------------- K4: scan pass A — thread owns all 16 states of one (d,chunk).
// B tile staged [t][n] in LDS (broadcast reads); dl/x direct global float4.
// grid.x = NCH-1: last chunk's (P,q) never needed by k5's exclusive prefix. ----
__global__ __launch_bounds__(256) void k4_scanA(
    const float* __restrict__ gdelta, const float* __restrict__ x,
    const float* __restrict__ gB,
    const float* __restrict__ Alog, const float* __restrict__ AlogB,
    float* __restrict__ Pbuf, float* __restrict__ qbuf) {
  __shared__ __align__(16) float sB[CT * 16];
  const int s = blockIdx.x;
  const int dir = blockIdx.y >> 2, b = blockIdx.y & 3;
  const int t0 = s * CT;
  const int tid = threadIdx.x;
  const int d = tid;                       // 256 threads == 256 d's
  const size_t ob = (size_t)dir * BN + b;

#pragma unroll
  for (int it = 0; it < 2; ++it) {
    int i = tid + it * 256;
    int n = i >> 5, t = i & 31;            // coalesced along t per n-row
    sB[t * 16 + n] = gB[(ob * NS + n) * LL + t0 + t];
  }
  __syncthreads();

  const float* Arow = (dir ? AlogB : Alog) + d * NS;
  float An2[16];
#pragma unroll
  for (int n = 0; n < 16; ++n) An2[n] = -__expf(Arow[n]) * LOG2E;

  const float* dlrow = gdelta + (ob * DD + d) * LL + t0;
  const float* xrow  = x + ((size_t)b * DD + d) * LL;

  float h[16];
#pragma unroll
  for (int n = 0; n < 16; ++n) h[n] = 0.f;
  float S = 0.f;

#define HUP(i, bv) h[i] = h[i] * __builtin_amdgcn_exp2f(dl * An2[i]) + dlx * (bv)

  for (int jb = 0; jb < CT; jb += 4) {
    float4 dl4 = *(const float4*)(dlrow + jb);
    float4 xv;
    if (dir == 0) {
      xv = *(const float4*)(xrow + t0 + jb);
    } else {
      float4 t = *(const float4*)(xrow + (LL - 4 - t0 - jb));
      xv = make_float4(t.w, t.z, t.y, t.x);
    }
    float dls[4] = {dl4.x, dl4.y, dl4.z, dl4.w};
    float xs[4]  = {xv.x, xv.y, xv.z, xv.w};
#pragma unroll
    for (int q = 0; q < 4; ++q) {
      float dl = dls[q];
      float dlx = dl * xs[q];
      S += dl;
      const float4* bp4 = (const float4*)&sB[(jb + q) * 16];
      float4 b0 = bp4[0], b1 = bp4[1], b2 = bp4[2], b3 = bp4[3];
      HUP(0, b0.x);  HUP(1, b0.y);  HUP(2, b0.z);  HUP(3, b0.w);
      HUP(4, b1.x);  HUP(5, b1.y);  HUP(6, b1.z);  HUP(7, b1.w);
      HUP(8, b2.x);  HUP(9, b2.y);  HUP(10, b2.z); HUP(11, b2.w);
      HUP(12, b3.x); HUP(13, b3.y); HUP(14, b3.z); HUP(15, b3.w);
    }
  }
#undef HUP

  float* Pp = Pbuf + ((ob * DD + d) * (size_t)NCH + s) * NS;
  float* qp = qbuf + ((ob * DD + d) * (size_t)NCH + s) * NS;
#pragma unroll
  for (int n = 0; n < 16; n += 4) {
    *(float4*)(Pp + n) = make_float4(
        __builtin_amdgcn_exp2f(An2[n + 0] * S), __builtin_amdgcn_exp2f(An2[n + 1] * S),
        __builtin_amdgcn_exp2f(An2[n + 2] * S), __builtin_amdgcn_exp2f(An2[n + 3] * S));
    *(float4*)(qp + n) = make_float4(h[n], h[n + 1], h[n + 2], h[n + 3]);
  }
}

// ---------------- K5: middle scan over chunks, loads batched 8-ahead ----------------
__global__ __launch_bounds__(64) void k5_mid(
    const float* __restrict__ Pbuf, float* __restrict__ qbuf) {
  int id = blockIdx.x * 64 + threadIdx.x;
  int n = id & 15;
  int d = (id >> 4) & 255;
  int rb = id >> 12;
  size_t base = (((size_t)rb * DD + d) * NCH) * NS + n;
  float h = 0.f;
  for (int s0 = 0; s0 < NCH; s0 += 8) {
    float Pv[8], qv[8];
#pragma unroll
    for (int k = 0; k < 8; ++k) {
      size_t idx = base + (size_t)(s0 + k) * NS;
      Pv[k] = Pbuf[idx];   // s=NCH-1: garbage, result discarded
      qv[k] = qbuf[idx];
    }
#pragma unroll
    for (int k = 0; k < 8; ++k) {
      size_t idx = base + (size_t)(s0 + k) * NS;
      qbuf[idx] = h;       // exclusive prefix: state at chunk start
      h = h * Pv[k] + qv[k];
    }
  }
}

// ---------------- K6: scan pass C — thread owns all 16 states; y-reduction in
// registers (4 partial accumulators); B/C staged [t][n] broadcast; no ylds. ----
__global__ __launch_bounds__(256) void k6_scanC(
    const float* __restrict__ gdelta, const float* __restrict__ x,
    const float* __restrict__ gB, const float* __restrict__ gC,
    const float* __restrict__ zb,
    const float* __restrict__ Alog, const float* __restrict__ AlogB,
    const float* __restrict__ Dvec, const float* __restrict__ DvecB,
    const float* __restrict__ hstart,
    float* __restrict__ y, float* __restrict__ yb) {
  __shared__ __align__(16) float sB[CT * 16];
  __shared__ __align__(16) float sC[CT * 16];
  const int s = blockIdx.x;
  const int dir = blockIdx.y >> 2, b = blockIdx.y & 3;
  const int t0 = s * CT;
  const int tid = threadIdx.x;
  const int d = tid;
  const size_t ob = (size_t)dir * BN + b;

#pragma unroll
  for (int it = 0; it < 2; ++it) {
    int i = tid + it * 256;
    int n = i >> 5, t = i & 31;
    sB[t * 16 + n] = gB[(ob * NS + n) * LL + t0 + t];
    sC[t * 16 + n] = gC[(ob * NS + n) * LL + t0 + t];
  }
  __syncthreads();

  const float* Arow = (dir ? AlogB : Alog) + d * NS;
  float An2[16];
#pragma unroll
  for (int n = 0; n < 16; ++n) An2[n] = -__expf(Arow[n]) * LOG2E;
  const float Dd = (dir ? DvecB : Dvec)[d];

  const float* hp = hstart + ((ob * DD + d) * (size_t)NCH + s) * NS;
  float h[16];
#pragma unroll
  for (int n = 0; n < 16; n += 4) {
    float4 hv = *(const float4*)(hp + n);
    h[n] = hv.x; h[n + 1] = hv.y; h[n + 2] = hv.z; h[n + 3] = hv.w;
  }

  const float* dlrow = gdelta + (ob * DD + d) * LL + t0;
  const float* xrow  = x + ((size_t)b * DD + d) * LL;
  const float* zrow  = zb + ((size_t)b * DD + d) * LL + t0;
  float* dst = (dir ? yb : y) + ((size_t)b * DD + d) * LL + t0;

#define HCC(i, bv, cv, acc) \
  h[i] = h[i] * __builtin_amdgcn_exp2f(dl * An2[i]) + dlx * (bv); acc += h[i] * (cv)

  for (int jb = 0; jb < CT; jb += 4) {
    float4 dl4 = *(const float4*)(dlrow + jb);
    float4 z4  = *(const float4*)(zrow + jb);
    float4 xv;
    if (dir == 0) {
      xv = *(const float4*)(xrow + t0 + jb);
    } else {
      float4 t = *(const float4*)(xrow + (LL - 4 - t0 - jb));
      xv = make_float4(t.w, t.z, t.y, t.x);
    }
    float dls[4] = {dl4.x, dl4.y, dl4.z, dl4.w};
    float xs[4]  = {xv.x, xv.y, xv.z, xv.w};
    float zs[4]  = {z4.x, z4.y, z4.z, z4.w};
    float yov[4];
#pragma unroll
    for (int q = 0; q < 4; ++q) {
      float dl = dls[q];
      float dlx = dl * xs[q];
      const float4* bp4 = (const float4*)&sB[(jb + q) * 16];
      const float4* cp4 = (const float4*)&sC[(jb + q) * 16];
      float4 b0 = bp4[0], b1 = bp4[1], b2 = bp4[2], b3 = bp4[3];
      float4 c0 = cp4[0], c1 = cp4[1], c2 = cp4[2], c3 = cp4[3];
      float a0 = 0.f, a1 = 0.f, a2 = 0.f, a3 = 0.f;
      HCC(0, b0.x, c0.x, a0);  HCC(1, b0.y, c0.y, a1);
      HCC(2, b0.z, c0.z, a2);  HCC(3, b0.w, c0.w, a3);
      HCC(4, b1.x, c1.x, a0);  HCC(5, b1.y, c1.y, a1);
      HCC(6, b1.z, c1.z, a2);  HCC(7, b1.w, c1.w, a3);
      HCC(8, b2.x, c2.x, a0);  HCC(9, b2.y, c2.y, a1);
      HCC(10, b2.z, c2.z, a2); HCC(11, b2.w, c2.w, a3);
      HCC(12, b3.x, c3.x, a0); HCC(13, b3.y, c3.y, a1);
      HCC(14, b3.z, c3.z, a2); HCC(15, b3.w, c3.w, a3);
      float ysum = (a0 + a1) + (a2 + a3);
      yov[q] = (ysum + Dd * xs[q]) * silu_f(zs[q]);
    }
    *(float4*)(dst + jb) = make_float4(yov[0], yov[1], yov[2], yov[3]);
  }
#undef HCC
}

// ---------------- K7: dual LayerNorm + double SiLU gate + flip-add ----------------
__global__ __launch_bounds__(256) void k7_final(
    const float* __restrict__ y, const float* __restrict__ yb,
    const float* __restrict__ zb,
    const float* __restrict__ lnw, const float* __restrict__ lnb,
    const float* __restrict__ ln1w, const float* __restrict__ ln1b,
    float* __restrict__ out) {
  __shared__ float sy[LL];
  __shared__ float syb[LL];
  __shared__ float rsum[4][4];
  const int row = blockIdx.x;
  const int tid = threadIdx.x;
  const size_t base = (size_t)row * LL;
  float s1y = 0.f, s2y = 0.f, s1b = 0.f, s2b = 0.f;
  for (int j = tid * 4; j < LL; j += 1024) {
    float4 v = *(const float4*)(y + base + j);
    *(float4*)&sy[j] = v;
    s1y += v.x + v.y + v.z + v.w;
    s2y += v.x * v.x + v.y * v.y + v.z * v.z + v.w * v.w;
    float4 w = *(const float4*)(yb + base + j);
    *(float4*)&syb[j] = w;
    s1b += w.x + w.y + w.z + w.w;
    s2b += w.x * w.x + w.y * w.y + w.z * w.z + w.w * w.w;
  }
#pragma unroll
  for (int m = 1; m < 64; m <<= 1) {
    s1y += __shfl_xor(s1y, m); s2y += __shfl_xor(s2y, m);
    s1b += __shfl_xor(s1b, m); s2b += __shfl_xor(s2b, m);
  }
  int wv = tid >> 6;
  if ((tid & 63) == 0) { rsum[wv][0] = s1y; rsum[wv][1] = s2y; rsum[wv][2] = s1b; rsum[wv][3] = s2b; }
  __syncthreads();
  float t1y = rsum[0][0] + rsum[1][0] + rsum[2][0] + rsum[3][0];
  float t2y = rsum[0][1] + rsum[1][1] + rsum[2][1] + rsum[3][1];
  float t1b = rsum[0][2] + rsum[1][2] + rsum[2][2] + rsum[3][2];
  float t2b = rsum[0][3] + rsum[1][3] + rsum[2][3] + rsum[3][3];
  const float inv = 1.f / (float)LL;
  float mY = t1y * inv; float vY = t2y * inv - mY * mY; float rY = rsqrtf(vY + 1e-5f);
  float mB = t1b * inv; float vB = t2b * inv - mB * mB; float rB = rsqrtf(vB + 1e-5f);
  for (int j = tid; j < LL; j += 256) {
    int jr = LL - 1 - j;
    float a  = (sy[j]  - mY) * rY * lnw[j]   + lnb[j];
    float g1 = silu_f(zb[base + j]);
    float bv = (syb[jr] - mB) * rB * ln1w[jr] + ln1b[jr];
    float g2 = silu_f(zb[base + jr]);
    out[base + j] = a * g1 + bv * g2;
  }
}

extern "C" void kernel_launch(void* const* d_in, const int* in_sizes, int n_in,
                              void* d_out, int out_size, void* d_ws, size_t ws_size,
                              hipStream_t stream) {
  const float* u     = (const float*)d_in[0];
  const float* inw   = (const float*)d_in[1];
  const float* cw    = (const float*)d_in[2];
  const float* cb    = (const float*)d_in[3];
  const float* xpw   = (const float*)d_in[4];
  const float* dtw   = (const float*)d_in[5];
  const float* dtb   = (const float*)d_in[6];
  const float* Alog  = (const float*)d_in[7];
  const float* Dv    = (const float*)d_in[8];
  const float* xpwB  = (const float*)d_in[9];
  const float* dtwB  = (const float*)d_in[10];
  const float* AlogB = (const float*)d_in[11];
  const float* DvB   = (const float*)d_in[12];
  const float* lnw   = (const float*)d_in[13];
  const float* lnb   = (const float*)d_in[14];
  const float* ln1w  = (const float*)d_in[15];
  const float* ln1b  = (const float*)d_in[16];
  float* out = (float*)d_out;

  float* ws = (float*)d_ws;
  const size_t SZ = (size_t)BN * DD * LL;        // 4,194,304 floats
  float* xpre   = ws;
  float* zb     = ws + SZ;
  float* xc     = ws + 2 * SZ;
  float* gdelta = ws + 3 * SZ;        // 2 dirs
  float* gB     = ws + 5 * SZ;
  float* gC     = gB + SZ / 8;
  float* Pbuf   = gC + SZ / 8;        // 2*4*256*128*16 = SZ floats (NCH=128)
  float* qbuf   = Pbuf + SZ;          // becomes hstart after k5_mid; total 7.25*SZ
  float* ybuf   = xpre;               // alias: xpre dead after k2
  float* ybbuf  = Pbuf;               // alias: Pbuf only read by k5, dead before k6 writes
  float* dtr    = Pbuf;               // alias: dtr dead (after k3b) before k4 writes Pbuf

  k1_mfma<<<dim3(64, 4, 4), 256, 0, stream>>>(inw, u, xpre, zb);
  k2_conv<<<1024, 256, 0, stream>>>(xpre, cw, cb, xc);
  k3_xproj<<<dim3(16, 4, 16), 256, 0, stream>>>(xc, xpw, xpwB, dtr, gB, gC);
  k3b_dtproj<<<dim3(16, 8, 4), 256, 0, stream>>>(dtr, dtw, dtwB, dtb, gdelta);
  k4_scanA<<<dim3(NCH - 1, 8), 256, 0, stream>>>(gdelta, xc, gB, Alog, AlogB, Pbuf, qbuf);
  k5_mid<<<512, 64, 0, stream>>>(Pbuf, qbuf);
  k6_scanC<<<dim3(NCH, 8), 256, 0, stream>>>(gdelta, xc, gB, gC, zb, Alog, AlogB,
                                             Dv, DvB, qbuf, ybuf, ybbuf);
  k7_final<<<1024, 256, 0, stream>>>(ybuf, ybbuf, zb, lnw, lnb, ln1w, ln1b, out);
}

// Round 2
// 280.634 us; speedup vs baseline: 1.7988x; 1.7988x over previous
//
#include <hip/hip_runtime.h>
#include <math.h>

#define BN 4
#define DD 256
#define LL 4096
#define NS 16
#define NCH 128  // scan chunks
#define CT 32    // chunk length (NCH*CT == LL)
#define SROW 36  // sdl/sx row stride (floats), 16B-aligned, 2-way-max read conflicts
#define BROW 20  // sB/sC row stride (floats), 80B = 16B-aligned, spreads banks
#define LOG2E 1.4426950408889634f

typedef __bf16 bf16x8 __attribute__((ext_vector_type(8)));
typedef float f32x4 __attribute__((ext_vector_type(4)));

__device__ __forceinline__ float softplus_f(float v) {
  return v > 20.f ? v : log1pf(__expf(v));
}
__device__ __forceinline__ float silu_f(float v) {
  return v / (1.f + __expf(-v));
}
__device__ __forceinline__ f32x4 exp2v(f32x4 a) {
  f32x4 r;
  r[0] = __builtin_amdgcn_exp2f(a[0]);
  r[1] = __builtin_amdgcn_exp2f(a[1]);
  r[2] = __builtin_amdgcn_exp2f(a[2]);
  r[3] = __builtin_amdgcn_exp2f(a[3]);
  return r;
}

// ---------------- K1: MFMA bf16 GEMM with inline f32->bf16 conversion ----------------
__global__ __launch_bounds__(256) void k1_mfma(
    const float* __restrict__ W, const float* __restrict__ u,
    float* __restrict__ xpre, float* __restrict__ zb) {
  __shared__ float Af[128 * 36];   // [e][k] f32, stride 36
  __shared__ float Bf[32 * 68];    // [k][l] f32, stride 68
  const int l0 = blockIdx.x * 64;
  const int e0 = blockIdx.y * 128;
  const int b  = blockIdx.z;
  const int tid = threadIdx.x;
  const int lane = tid & 63, w = tid >> 6;
  const int m16 = lane & 15, quad = lane >> 4;

  f32x4 acc[2][4];
#pragma unroll
  for (int i = 0; i < 2; ++i)
#pragma unroll
    for (int j = 0; j < 4; ++j) acc[i][j] = (f32x4){0.f, 0.f, 0.f, 0.f};

  const float* Ub = u + (size_t)b * DD * LL;

  for (int k0 = 0; k0 < DD; k0 += 32) {
    if (k0) __syncthreads();
#pragma unroll
    for (int it = 0; it < 4; ++it) {
      int f4 = tid + it * 256;
      int e = f4 >> 3, kq = f4 & 7;
      *(float4*)&Af[e * 36 + kq * 4] =
          *(const float4*)(W + (size_t)(e0 + e) * DD + k0 + kq * 4);
    }
#pragma unroll
    for (int it = 0; it < 2; ++it) {
      int f4 = tid + it * 256;
      int kk = f4 >> 4, lq = f4 & 15;
      *(float4*)&Bf[kk * 68 + lq * 4] =
          *(const float4*)(Ub + (size_t)(k0 + kk) * LL + l0 + lq * 4);
    }
    __syncthreads();
    bf16x8 afr[2], bfr[4];
#pragma unroll
    for (int te = 0; te < 2; ++te) {
      const float* src = &Af[(w * 32 + te * 16 + m16) * 36 + quad * 8];
      bf16x8 t;
#pragma unroll
      for (int j = 0; j < 8; ++j) t[j] = (__bf16)src[j];
      afr[te] = t;
    }
#pragma unroll
    for (int tl = 0; tl < 4; ++tl) {
      bf16x8 t;
#pragma unroll
      for (int j = 0; j < 8; ++j) t[j] = (__bf16)Bf[(quad * 8 + j) * 68 + tl * 16 + m16];
      bfr[tl] = t;
    }
#pragma unroll
    for (int te = 0; te < 2; ++te)
#pragma unroll
      for (int tl = 0; tl < 4; ++tl)
        acc[te][tl] = __builtin_amdgcn_mfma_f32_16x16x32_bf16(afr[te], bfr[tl], acc[te][tl], 0, 0, 0);
  }

#pragma unroll
  for (int te = 0; te < 2; ++te) {
#pragma unroll
    for (int tl = 0; tl < 4; ++tl) {
      int col = l0 + tl * 16 + m16;
#pragma unroll
      for (int r = 0; r < 4; ++r) {
        int e = e0 + w * 32 + te * 16 + quad * 4 + r;
        float v = acc[te][tl][r];
        if (e < DD) xpre[((size_t)b * DD + e) * LL + col] = v;
        else        zb[((size_t)b * DD + (e - DD)) * LL + col] = v;
      }
    }
  }
}

// ---------------- K2: depthwise conv == 3-tap along d, weights per l ----------------
__global__ __launch_bounds__(256) void k2_conv(
    const float* __restrict__ xpre, const float* __restrict__ cw,
    const float* __restrict__ cb, float* __restrict__ xo) {
  const int bd = blockIdx.x;       // b*256 + d
  const int d = bd & 255;
  const size_t row = (size_t)bd * LL;
  const float* r1 = xpre + row;
  const bool has0 = d > 0, has2 = d < DD - 1;
  for (int j = threadIdx.x; j < LL; j += 256) {
    float w0 = cw[j * 9 + 3], w1 = cw[j * 9 + 4], w2 = cw[j * 9 + 5];
    float v = cb[j] + r1[j] * w1;
    if (has0) v += r1[j - LL] * w0;
    if (has2) v += r1[j + LL] * w2;
    xo[row + j] = v;
  }
}

// ---------------- K3: x_proj GEMM, 6 rows/block, no LDS / no barriers ----------
__global__ __launch_bounds__(256) void k3_xproj(
    const float* __restrict__ xc,
    const float* __restrict__ xpw, const float* __restrict__ xpwB,
    float* __restrict__ dtr, float* __restrict__ gB, float* __restrict__ gC) {
  const int tid = threadIdx.x;
  const int l   = blockIdx.x * 256 + tid;
  const int b   = blockIdx.y;
  const int zz  = blockIdx.z;            // dir*8 + rg
  const int dir = zz >> 3, rg = zz & 7;
  const int rbase = rg * 6;
  const float* W = (dir ? xpwB : xpw) + (size_t)rbase * DD;   // 6 rows x 256
  const float* xcol = xc + (size_t)b * DD * LL + l;

  float acc[6] = {0.f, 0.f, 0.f, 0.f, 0.f, 0.f};

#pragma unroll 8
  for (int d = 0; d < DD; ++d) {
    float xv = xcol[(size_t)d * LL];
#pragma unroll
    for (int i = 0; i < 6; ++i) acc[i] += W[i * DD + d] * xv;
  }

  const size_t ob = ((size_t)dir * BN + b);
#pragma unroll
  for (int i = 0; i < 6; ++i) {
    int r = rbase + i;
    if (r < 16)
      dtr[(ob * 16 + r) * LL + l] = acc[i];
    else if (r < 32)
      gB[(ob * NS + (r - 16)) * LL + l] = acc[i];
    else
      gC[(ob * NS + (r - 32)) * LL + l] = acc[i];
  }
}

// ---------------- K3b: dt_proj + softplus -> gdelta; dtr register-cached ----------
__global__ __launch_bounds__(256) void k3b_dtproj(
    const float* __restrict__ dtr,
    const float* __restrict__ dtw, const float* __restrict__ dtwB,
    const float* __restrict__ dtb,
    float* __restrict__ gdelta) {
  const int tid = threadIdx.x;
  const int l   = blockIdx.x * 256 + tid;
  const int b   = blockIdx.y & 3;
  const int dir = blockIdx.y >> 2;
  const int d0  = blockIdx.z * 64;
  const size_t ob = ((size_t)dir * BN + b);
  const float* dw = (dir ? dtwB : dtw);

  float tr[16];
#pragma unroll
  for (int r = 0; r < 16; ++r) tr[r] = dtr[(ob * 16 + r) * LL + l];

#pragma unroll 4
  for (int d = d0; d < d0 + 64; ++d) {
    float acc = dtb[d];
#pragma unroll
    for (int r = 0; r < 16; ++r) acc += dw[d * 16 + r] * tr[r];
    gdelta[(ob * DD + d) * LL + l] = softplus_f(acc);
  }
}

// ---------------- K4: scan pass A — block = 64 d x CT, thread = (d, 4 states).
// Coalesced staging of dl/x into LDS; B staged [t][n] (stride 20, bank-spread);
// per-step: 1 b128 B read (4 bcast addrs) + 0.5 b128 dl/x; f32x4 packed math. ----
__global__ __launch_bounds__(256) void k4_scanA(
    const float* __restrict__ gdelta, const float* __restrict__ x,
    const float* __restrict__ gB,
    const float* __restrict__ Alog, const float* __restrict__ AlogB,
    float* __restrict__ Pbuf, float* __restrict__ qbuf) {
  __shared__ float sdl[64 * SROW];
  __shared__ float sx[64 * SROW];
  __shared__ float sB[CT * BROW];
  const int s = blockIdx.x;
  const int d0 = blockIdx.y * 64;
  const int dir = blockIdx.z >> 2, b = blockIdx.z & 3;
  const int t0 = s * CT;
  const int tid = threadIdx.x;
  const size_t ob = (size_t)dir * BN + b;

  {
    const int q = tid & 7, r2 = tid >> 3;   // 32 rows per pass, q = float4 col
#pragma unroll
    for (int p = 0; p < 2; ++p) {
      int row = r2 + p * 32;
      f32x4 dl = *(const f32x4*)(gdelta + (ob * DD + d0 + row) * LL + t0 + q * 4);
      f32x4 xv;
      if (dir == 0) {
        xv = *(const f32x4*)(x + ((size_t)b * DD + d0 + row) * LL + t0 + q * 4);
      } else {
        f32x4 t = *(const f32x4*)(x + ((size_t)b * DD + d0 + row) * LL + (LL - 4 - t0 - q * 4));
        xv = (f32x4){t[3], t[2], t[1], t[0]};
      }
      *(f32x4*)&sdl[row * SROW + q * 4] = dl;
      *(f32x4*)&sx[row * SROW + q * 4] = xv;
    }
    const int t = tid & 31, n8 = tid >> 5;
#pragma unroll
    for (int p = 0; p < 2; ++p) {
      int n = n8 + p * 8;
      sB[t * BROW + n] = gB[(ob * NS + n) * LL + t0 + t];
    }
  }
  __syncthreads();

  const int dq = tid >> 2, sub = tid & 3, n0 = sub * 4;
  const int d = d0 + dq;
  f32x4 Al = *(const f32x4*)((dir ? AlogB : Alog) + d * NS + n0);
  f32x4 An2;
  An2[0] = -__expf(Al[0]) * LOG2E;
  An2[1] = -__expf(Al[1]) * LOG2E;
  An2[2] = -__expf(Al[2]) * LOG2E;
  An2[3] = -__expf(Al[3]) * LOG2E;

  f32x4 h = (f32x4){0.f, 0.f, 0.f, 0.f};
  float S = 0.f;

  for (int jb = 0; jb < CT; jb += 4) {
    f32x4 dl4 = *(const f32x4*)&sdl[dq * SROW + jb];
    f32x4 x4  = *(const f32x4*)&sx[dq * SROW + jb];
#pragma unroll
    for (int q = 0; q < 4; ++q) {
      int t = jb + q;
      f32x4 Bv = *(const f32x4*)&sB[t * BROW + n0];
      float dl = dl4[q];
      float dlx = dl * x4[q];
      f32x4 e = exp2v(dl * An2);
      h = h * e + dlx * Bv;
      S += dl;
    }
  }

  const size_t pidx = ((ob * DD + d) * (size_t)NCH + s) * NS + n0;
  *(f32x4*)(Pbuf + pidx) = exp2v(An2 * S);   // quad writes 64B contiguous
  *(f32x4*)(qbuf + pidx) = h;
}

// ---------------- K5: middle scan over chunks, loads batched 8-ahead ----------------
__global__ __launch_bounds__(64) void k5_mid(
    const float* __restrict__ Pbuf, float* __restrict__ qbuf) {
  int id = blockIdx.x * 64 + threadIdx.x;
  int n = id & 15;
  int d = (id >> 4) & 255;
  int rb = id >> 12;
  size_t base = (((size_t)rb * DD + d) * NCH) * NS + n;
  float h = 0.f;
  for (int s0 = 0; s0 < NCH; s0 += 8) {
    float Pv[8], qv[8];
#pragma unroll
    for (int k = 0; k < 8; ++k) {
      size_t idx = base + (size_t)(s0 + k) * NS;
      Pv[k] = Pbuf[idx];   // s=NCH-1: garbage, result discarded
      qv[k] = qbuf[idx];
    }
#pragma unroll
    for (int k = 0; k < 8; ++k) {
      size_t idx = base + (size_t)(s0 + k) * NS;
      qbuf[idx] = h;       // exclusive prefix: state at chunk start
      h = h * Pv[k] + qv[k];
    }
  }
}

// ---------------- K6: scan pass C — thread = (d, 4 states); coalesced staging;
// quad partials to small ylds, intra-wave flush every 8 steps (no barriers). ----
__global__ __launch_bounds__(256) void k6_scanC(
    const float* __restrict__ gdelta, const float* __restrict__ x,
    const float* __restrict__ gB, const float* __restrict__ gC,
    const float* __restrict__ zb,
    const float* __restrict__ Alog, const float* __restrict__ AlogB,
    const float* __restrict__ Dvec, const float* __restrict__ DvecB,
    const float* __restrict__ hstart,
    float* __restrict__ y, float* __restrict__ yb) {
  __shared__ float sdl[64 * SROW];
  __shared__ float sx[64 * SROW];
  __shared__ float sB[CT * BROW];
  __shared__ float sC[CT * BROW];
  __shared__ float ylds[64 * 36];   // [d][tb*4 + sub], stride 36 (2-way max)
  __shared__ float sD[64];
  const int s = blockIdx.x;
  const int d0 = blockIdx.y * 64;
  const int dir = blockIdx.z >> 2, b = blockIdx.z & 3;
  const int t0 = s * CT;
  const int tid = threadIdx.x;
  const size_t ob = (size_t)dir * BN + b;

  {
    const int q = tid & 7, r2 = tid >> 3;
#pragma unroll
    for (int p = 0; p < 2; ++p) {
      int row = r2 + p * 32;
      f32x4 dl = *(const f32x4*)(gdelta + (ob * DD + d0 + row) * LL + t0 + q * 4);
      f32x4 xv;
      if (dir == 0) {
        xv = *(const f32x4*)(x + ((size_t)b * DD + d0 + row) * LL + t0 + q * 4);
      } else {
        f32x4 t = *(const f32x4*)(x + ((size_t)b * DD + d0 + row) * LL + (LL - 4 - t0 - q * 4));
        xv = (f32x4){t[3], t[2], t[1], t[0]};
      }
      *(f32x4*)&sdl[row * SROW + q * 4] = dl;
      *(f32x4*)&sx[row * SROW + q * 4] = xv;
    }
    const int t = tid & 31, n8 = tid >> 5;
#pragma unroll
    for (int p = 0; p < 2; ++p) {
      int n = n8 + p * 8;
      sB[t * BROW + n] = gB[(ob * NS + n) * LL + t0 + t];
      sC[t * BROW + n] = gC[(ob * NS + n) * LL + t0 + t];
    }
    if (tid < 64) sD[tid] = (dir ? DvecB : Dvec)[d0 + tid];
  }
  __syncthreads();

  const int dq = tid >> 2, sub = tid & 3, n0 = sub * 4;
  const int lane = tid & 63, w = tid >> 6;
  const int d = d0 + dq;
  f32x4 Al = *(const f32x4*)((dir ? AlogB : Alog) + d * NS + n0);
  f32x4 An2;
  An2[0] = -__expf(Al[0]) * LOG2E;
  An2[1] = -__expf(Al[1]) * LOG2E;
  An2[2] = -__expf(Al[2]) * LOG2E;
  An2[3] = -__expf(Al[3]) * LOG2E;

  const size_t pidx = ((ob * DD + d) * (size_t)NCH + s) * NS + n0;
  f32x4 h = *(const f32x4*)(hstart + pidx);

  const float* zbase = zb + ((size_t)b * DD + d0) * LL + t0;
  float* dbase = (dir ? yb : y) + ((size_t)b * DD + d0) * LL + t0;
  const int dql = lane >> 3, tql = lane & 7;   // flush mapping (intra-wave)

  for (int jb = 0; jb < CT; jb += 8) {
#pragma unroll
    for (int j2 = 0; j2 < 8; j2 += 4) {
      f32x4 dl4 = *(const f32x4*)&sdl[dq * SROW + jb + j2];
      f32x4 x4  = *(const f32x4*)&sx[dq * SROW + jb + j2];
#pragma unroll
      for (int q = 0; q < 4; ++q) {
        int t = jb + j2 + q;
        f32x4 Bv = *(const f32x4*)&sB[t * BROW + n0];
        f32x4 Cv = *(const f32x4*)&sC[t * BROW + n0];
        float dl = dl4[q];
        float dlx = dl * x4[q];
        f32x4 e = exp2v(dl * An2);
        h = h * e + dlx * Bv;
        f32x4 yc = h * Cv;
        ylds[dq * 36 + ((j2 + q) << 2) + sub] = (yc[0] + yc[1]) + (yc[2] + yc[3]);
      }
    }
    // flush: wave w covers d = w*16..w*16+15; reads only its own writes (in-order DS)
#pragma unroll
    for (int k = 0; k < 2; ++k) {
      int dd = w * 16 + dql + 8 * k;
      int tt = jb + tql;
      f32x4 pv = *(const f32x4*)&ylds[dd * 36 + tql * 4];
      float sum = (pv[0] + pv[1]) + (pv[2] + pv[3]);
      float xv = sx[dd * SROW + tt];
      float zv = zbase[(size_t)dd * LL + tt];
      dbase[(size_t)dd * LL + tt] = (sum + sD[dd] * xv) * silu_f(zv);
    }
  }
}

// ---------------- K7: dual LayerNorm + double SiLU gate + flip-add ----------------
__global__ __launch_bounds__(256) void k7_final(
    const float* __restrict__ y, const float* __restrict__ yb,
    const float* __restrict__ zb,
    const float* __restrict__ lnw, const float* __restrict__ lnb,
    const float* __restrict__ ln1w, const float* __restrict__ ln1b,
    float* __restrict__ out) {
  __shared__ float sy[LL];
  __shared__ float syb[LL];
  __shared__ float rsum[4][4];
  const int row = blockIdx.x;
  const int tid = threadIdx.x;
  const size_t base = (size_t)row * LL;
  float s1y = 0.f, s2y = 0.f, s1b = 0.f, s2b = 0.f;
  for (int j = tid * 4; j < LL; j += 1024) {
    float4 v = *(const float4*)(y + base + j);
    *(float4*)&sy[j] = v;
    s1y += v.x + v.y + v.z + v.w;
    s2y += v.x * v.x + v.y * v.y + v.z * v.z + v.w * v.w;
    float4 w = *(const float4*)(yb + base + j);
    *(float4*)&syb[j] = w;
    s1b += w.x + w.y + w.z + w.w;
    s2b += w.x * w.x + w.y * w.y + w.z * w.z + w.w * w.w;
  }
#pragma unroll
  for (int m = 1; m < 64; m <<= 1) {
    s1y += __shfl_xor(s1y, m); s2y += __shfl_xor(s2y, m);
    s1b += __shfl_xor(s1b, m); s2b += __shfl_xor(s2b, m);
  }
  int wv = tid >> 6;
  if ((tid & 63) == 0) { rsum[wv][0] = s1y; rsum[wv][1] = s2y; rsum[wv][2] = s1b; rsum[wv][3] = s2b; }
  __syncthreads();
  float t1y = rsum[0][0] + rsum[1][0] + rsum[2][0] + rsum[3][0];
  float t2y = rsum[0][1] + rsum[1][1] + rsum[2][1] + rsum[3][1];
  float t1b = rsum[0][2] + rsum[1][2] + rsum[2][2] + rsum[3][2];
  float t2b = rsum[0][3] + rsum[1][3] + rsum[2][3] + rsum[3][3];
  const float inv = 1.f / (float)LL;
  float mY = t1y * inv; float vY = t2y * inv - mY * mY; float rY = rsqrtf(vY + 1e-5f);
  float mB = t1b * inv; float vB = t2b * inv - mB * mB; float rB = rsqrtf(vB + 1e-5f);
  for (int j = tid; j < LL; j += 256) {
    int jr = LL - 1 - j;
    float a  = (sy[j]  - mY) * rY * lnw[j]   + lnb[j];
    float g1 = silu_f(zb[base + j]);
    float bv = (syb[jr] - mB) * rB * ln1w[jr] + ln1b[jr];
    float g2 = silu_f(zb[base + jr]);
    out[base + j] = a * g1 + bv * g2;
  }
}

extern "C" void kernel_launch(void* const* d_in, const int* in_sizes, int n_in,
                              void* d_out, int out_size, void* d_ws, size_t ws_size,
                              hipStream_t stream) {
  const float* u     = (const float*)d_in[0];
  const float* inw   = (const float*)d_in[1];
  const float* cw    = (const float*)d_in[2];
  const float* cb    = (const float*)d_in[3];
  const float* xpw   = (const float*)d_in[4];
  const float* dtw   = (const float*)d_in[5];
  const float* dtb   = (const float*)d_in[6];
  const float* Alog  = (const float*)d_in[7];
  const float* Dv    = (const float*)d_in[8];
  const float* xpwB  = (const float*)d_in[9];
  const float* dtwB  = (const float*)d_in[10];
  const float* AlogB = (const float*)d_in[11];
  const float* DvB   = (const float*)d_in[12];
  const float* lnw   = (const float*)d_in[13];
  const float* lnb   = (const float*)d_in[14];
  const float* ln1w  = (const float*)d_in[15];
  const float* ln1b  = (const float*)d_in[16];
  float* out = (float*)d_out;

  float* ws = (float*)d_ws;
  const size_t SZ = (size_t)BN * DD * LL;        // 4,194,304 floats
  float* xpre   = ws;
  float* zb     = ws + SZ;
  float* xc     = ws + 2 * SZ;
  float* gdelta = ws + 3 * SZ;        // 2 dirs
  float* gB     = ws + 5 * SZ;
  float* gC     = gB + SZ / 8;
  float* Pbuf   = gC + SZ / 8;        // 2*4*256*128*16 = SZ floats (NCH=128)
  float* qbuf   = Pbuf + SZ;          // becomes hstart after k5_mid; total 7.25*SZ
  float* ybuf   = xpre;               // alias: xpre dead after k2
  float* ybbuf  = Pbuf;               // alias: Pbuf only read by k5, dead before k6 writes
  float* dtr    = Pbuf;               // alias: dtr dead (after k3b) before k4 writes Pbuf

  k1_mfma<<<dim3(64, 4, 4), 256, 0, stream>>>(inw, u, xpre, zb);
  k2_conv<<<1024, 256, 0, stream>>>(xpre, cw, cb, xc);
  k3_xproj<<<dim3(16, 4, 16), 256, 0, stream>>>(xc, xpw, xpwB, dtr, gB, gC);
  k3b_dtproj<<<dim3(16, 8, 4), 256, 0, stream>>>(dtr, dtw, dtwB, dtb, gdelta);
  k4_scanA<<<dim3(NCH - 1, 4, 8), 256, 0, stream>>>(gdelta, xc, gB, Alog, AlogB, Pbuf, qbuf);
  k5_mid<<<512, 64, 0, stream>>>(Pbuf, qbuf);
  k6_scanC<<<dim3(NCH, 4, 8), 256, 0, stream>>>(gdelta, xc, gB, gC, zb, Alog, AlogB,
                                                Dv, DvB, qbuf, ybuf, ybbuf);
  k7_final<<<1024, 256, 0, stream>>>(ybuf, ybbuf, zb, lnw, lnb, ln1w, ln1b, out);
}

// Round 3
// 245.260 us; speedup vs baseline: 2.0583x; 1.1442x over previous
//
#include <hip/hip_runtime.h>
#include <math.h>

#define BN 4
#define DD 256
#define LL 4096
#define NS 16
#define NCH 128  // scan chunks
#define CT 32    // chunk length (NCH*CT == LL)
#define SROW 36  // sdl/sx row stride (floats), 16B-aligned, 2-way-max read conflicts
#define BROW 20  // sB/sC row stride (floats), 80B = 16B-aligned, spreads banks
#define LOG2E 1.4426950408889634f

typedef __bf16 bf16x8 __attribute__((ext_vector_type(8)));
typedef float f32x4 __attribute__((ext_vector_type(4)));

__device__ __forceinline__ float softplus_f(float v) {
  // ln(1+e^v) via native exp2/log2; branchless guard for large v (inf-safe).
  float e = __builtin_amdgcn_exp2f(v * LOG2E);
  float r = 0.69314718056f * __builtin_amdgcn_logf(1.f + e);
  return v > 20.f ? v : r;
}
__device__ __forceinline__ float silu_f(float v) {
  return v / (1.f + __expf(-v));
}
__device__ __forceinline__ f32x4 exp2v(f32x4 a) {
  f32x4 r;
  r[0] = __builtin_amdgcn_exp2f(a[0]);
  r[1] = __builtin_amdgcn_exp2f(a[1]);
  r[2] = __builtin_amdgcn_exp2f(a[2]);
  r[3] = __builtin_amdgcn_exp2f(a[3]);
  return r;
}

// ---------------- K1: MFMA bf16 GEMM with inline f32->bf16 conversion ----------------
__global__ __launch_bounds__(256) void k1_mfma(
    const float* __restrict__ W, const float* __restrict__ u,
    float* __restrict__ xpre, float* __restrict__ zb) {
  __shared__ float Af[128 * 36];   // [e][k] f32, stride 36
  __shared__ float Bf[32 * 68];    // [k][l] f32, stride 68
  const int l0 = blockIdx.x * 64;
  const int e0 = blockIdx.y * 128;
  const int b  = blockIdx.z;
  const int tid = threadIdx.x;
  const int lane = tid & 63, w = tid >> 6;
  const int m16 = lane & 15, quad = lane >> 4;

  f32x4 acc[2][4];
#pragma unroll
  for (int i = 0; i < 2; ++i)
#pragma unroll
    for (int j = 0; j < 4; ++j) acc[i][j] = (f32x4){0.f, 0.f, 0.f, 0.f};

  const float* Ub = u + (size_t)b * DD * LL;

  for (int k0 = 0; k0 < DD; k0 += 32) {
    if (k0) __syncthreads();
#pragma unroll
    for (int it = 0; it < 4; ++it) {
      int f4 = tid + it * 256;
      int e = f4 >> 3, kq = f4 & 7;
      *(float4*)&Af[e * 36 + kq * 4] =
          *(const float4*)(W + (size_t)(e0 + e) * DD + k0 + kq * 4);
    }
#pragma unroll
    for (int it = 0; it < 2; ++it) {
      int f4 = tid + it * 256;
      int kk = f4 >> 4, lq = f4 & 15;
      *(float4*)&Bf[kk * 68 + lq * 4] =
          *(const float4*)(Ub + (size_t)(k0 + kk) * LL + l0 + lq * 4);
    }
    __syncthreads();
    bf16x8 afr[2], bfr[4];
#pragma unroll
    for (int te = 0; te < 2; ++te) {
      const float* src = &Af[(w * 32 + te * 16 + m16) * 36 + quad * 8];
      bf16x8 t;
#pragma unroll
      for (int j = 0; j < 8; ++j) t[j] = (__bf16)src[j];
      afr[te] = t;
    }
#pragma unroll
    for (int tl = 0; tl < 4; ++tl) {
      bf16x8 t;
#pragma unroll
      for (int j = 0; j < 8; ++j) t[j] = (__bf16)Bf[(quad * 8 + j) * 68 + tl * 16 + m16];
      bfr[tl] = t;
    }
#pragma unroll
    for (int te = 0; te < 2; ++te)
#pragma unroll
      for (int tl = 0; tl < 4; ++tl)
        acc[te][tl] = __builtin_amdgcn_mfma_f32_16x16x32_bf16(afr[te], bfr[tl], acc[te][tl], 0, 0, 0);
  }

#pragma unroll
  for (int te = 0; te < 2; ++te) {
#pragma unroll
    for (int tl = 0; tl < 4; ++tl) {
      int col = l0 + tl * 16 + m16;
#pragma unroll
      for (int r = 0; r < 4; ++r) {
        int e = e0 + w * 32 + te * 16 + quad * 4 + r;
        float v = acc[te][tl][r];
        if (e < DD) xpre[((size_t)b * DD + e) * LL + col] = v;
        else        zb[((size_t)b * DD + (e - DD)) * LL + col] = v;
      }
    }
  }
}

// ---------------- K2: depthwise conv == 3-tap along d, weights per l ----------------
__global__ __launch_bounds__(256) void k2_conv(
    const float* __restrict__ xpre, const float* __restrict__ cw,
    const float* __restrict__ cb, float* __restrict__ xo) {
  const int bd = blockIdx.x;       // b*256 + d
  const int d = bd & 255;
  const size_t row = (size_t)bd * LL;
  const float* r1 = xpre + row;
  const bool has0 = d > 0, has2 = d < DD - 1;
  for (int j = threadIdx.x; j < LL; j += 256) {
    float w0 = cw[j * 9 + 3], w1 = cw[j * 9 + 4], w2 = cw[j * 9 + 5];
    float v = cb[j] + r1[j] * w1;
    if (has0) v += r1[j - LL] * w0;
    if (has2) v += r1[j + LL] * w2;
    xo[row + j] = v;
  }
}

// ---------------- K3: x_proj GEMM, 6 rows/block, no LDS / no barriers ----------
__global__ __launch_bounds__(256) void k3_xproj(
    const float* __restrict__ xc,
    const float* __restrict__ xpw, const float* __restrict__ xpwB,
    float* __restrict__ dtr, float* __restrict__ gB, float* __restrict__ gC) {
  const int tid = threadIdx.x;
  const int l   = blockIdx.x * 256 + tid;
  const int b   = blockIdx.y;
  const int zz  = blockIdx.z;            // dir*8 + rg
  const int dir = zz >> 3, rg = zz & 7;
  const int rbase = rg * 6;
  const float* W = (dir ? xpwB : xpw) + (size_t)rbase * DD;   // 6 rows x 256
  const float* xcol = xc + (size_t)b * DD * LL + l;

  float acc[6] = {0.f, 0.f, 0.f, 0.f, 0.f, 0.f};

#pragma unroll 8
  for (int d = 0; d < DD; ++d) {
    float xv = xcol[(size_t)d * LL];
#pragma unroll
    for (int i = 0; i < 6; ++i) acc[i] += W[i * DD + d] * xv;
  }

  const size_t ob = ((size_t)dir * BN + b);
#pragma unroll
  for (int i = 0; i < 6; ++i) {
    int r = rbase + i;
    if (r < 16)
      dtr[(ob * 16 + r) * LL + l] = acc[i];
    else if (r < 32)
      gB[(ob * NS + (r - 16)) * LL + l] = acc[i];
    else
      gC[(ob * NS + (r - 32)) * LL + l] = acc[i];
  }
}

// ---------------- K3b: dt_proj + fast softplus -> gdelta; 16 d/block for
// 8 blocks/CU occupancy; dtr register-cached; native exp2/log2 softplus. ----
__global__ __launch_bounds__(256) void k3b_dtproj(
    const float* __restrict__ dtr,
    const float* __restrict__ dtw, const float* __restrict__ dtwB,
    const float* __restrict__ dtb,
    float* __restrict__ gdelta) {
  const int tid = threadIdx.x;
  const int l   = blockIdx.x * 256 + tid;
  const int b   = blockIdx.y & 3;
  const int dir = blockIdx.y >> 2;
  const int d0  = blockIdx.z * 16;
  const size_t ob = ((size_t)dir * BN + b);
  const float* dw = (dir ? dtwB : dtw);

  float tr[16];
#pragma unroll
  for (int r = 0; r < 16; ++r) tr[r] = dtr[(ob * 16 + r) * LL + l];

#pragma unroll
  for (int d = d0; d < d0 + 16; ++d) {
    float acc = dtb[d];
#pragma unroll
    for (int r = 0; r < 16; ++r) acc += dw[d * 16 + r] * tr[r];
    gdelta[(ob * DD + d) * LL + l] = softplus_f(acc);
  }
}

// ---------------- K4: scan pass A — block = 64 d x CT, thread = (d, 4 states).
// Coalesced staging of dl/x into LDS; B staged [t][n] (stride 20, bank-spread);
// per-step: 1 b128 B read (4 bcast addrs) + 0.5 b128 dl/x; f32x4 packed math. ----
__global__ __launch_bounds__(256) void k4_scanA(
    const float* __restrict__ gdelta, const float* __restrict__ x,
    const float* __restrict__ gB,
    const float* __restrict__ Alog, const float* __restrict__ AlogB,
    float* __restrict__ Pbuf, float* __restrict__ qbuf) {
  __shared__ float sdl[64 * SROW];
  __shared__ float sx[64 * SROW];
  __shared__ float sB[CT * BROW];
  const int s = blockIdx.x;
  const int d0 = blockIdx.y * 64;
  const int dir = blockIdx.z >> 2, b = blockIdx.z & 3;
  const int t0 = s * CT;
  const int tid = threadIdx.x;
  const size_t ob = (size_t)dir * BN + b;

  {
    const int q = tid & 7, r2 = tid >> 3;   // 32 rows per pass, q = float4 col
#pragma unroll
    for (int p = 0; p < 2; ++p) {
      int row = r2 + p * 32;
      f32x4 dl = *(const f32x4*)(gdelta + (ob * DD + d0 + row) * LL + t0 + q * 4);
      f32x4 xv;
      if (dir == 0) {
        xv = *(const f32x4*)(x + ((size_t)b * DD + d0 + row) * LL + t0 + q * 4);
      } else {
        f32x4 t = *(const f32x4*)(x + ((size_t)b * DD + d0 + row) * LL + (LL - 4 - t0 - q * 4));
        xv = (f32x4){t[3], t[2], t[1], t[0]};
      }
      *(f32x4*)&sdl[row * SROW + q * 4] = dl;
      *(f32x4*)&sx[row * SROW + q * 4] = xv;
    }
    const int t = tid & 31, n8 = tid >> 5;
#pragma unroll
    for (int p = 0; p < 2; ++p) {
      int n = n8 + p * 8;
      sB[t * BROW + n] = gB[(ob * NS + n) * LL + t0 + t];
    }
  }
  __syncthreads();

  const int dq = tid >> 2, sub = tid & 3, n0 = sub * 4;
  const int d = d0 + dq;
  f32x4 Al = *(const f32x4*)((dir ? AlogB : Alog) + d * NS + n0);
  f32x4 An2;
  An2[0] = -__expf(Al[0]) * LOG2E;
  An2[1] = -__expf(Al[1]) * LOG2E;
  An2[2] = -__expf(Al[2]) * LOG2E;
  An2[3] = -__expf(Al[3]) * LOG2E;

  f32x4 h = (f32x4){0.f, 0.f, 0.f, 0.f};
  float S = 0.f;

  for (int jb = 0; jb < CT; jb += 4) {
    f32x4 dl4 = *(const f32x4*)&sdl[dq * SROW + jb];
    f32x4 x4  = *(const f32x4*)&sx[dq * SROW + jb];
#pragma unroll
    for (int q = 0; q < 4; ++q) {
      int t = jb + q;
      f32x4 Bv = *(const f32x4*)&sB[t * BROW + n0];
      float dl = dl4[q];
      float dlx = dl * x4[q];
      f32x4 e = exp2v(dl * An2);
      h = h * e + dlx * Bv;
      S += dl;
    }
  }

  const size_t pidx = ((ob * DD + d) * (size_t)NCH + s) * NS + n0;
  *(f32x4*)(Pbuf + pidx) = exp2v(An2 * S);   // quad writes 64B contiguous
  *(f32x4*)(qbuf + pidx) = h;
}

// ---------------- K5: middle scan over chunks, loads batched 8-ahead ----------------
__global__ __launch_bounds__(64) void k5_mid(
    const float* __restrict__ Pbuf, float* __restrict__ qbuf) {
  int id = blockIdx.x * 64 + threadIdx.x;
  int n = id & 15;
  int d = (id >> 4) & 255;
  int rb = id >> 12;
  size_t base = (((size_t)rb * DD + d) * NCH) * NS + n;
  float h = 0.f;
  for (int s0 = 0; s0 < NCH; s0 += 8) {
    float Pv[8], qv[8];
#pragma unroll
    for (int k = 0; k < 8; ++k) {
      size_t idx = base + (size_t)(s0 + k) * NS;
      Pv[k] = Pbuf[idx];   // s=NCH-1: garbage, result discarded
      qv[k] = qbuf[idx];
    }
#pragma unroll
    for (int k = 0; k < 8; ++k) {
      size_t idx = base + (size_t)(s0 + k) * NS;
      qbuf[idx] = h;       // exclusive prefix: state at chunk start
      h = h * Pv[k] + qv[k];
    }
  }
}

// ---------------- K6: scan pass C — thread = (d, 4 states); coalesced staging;
// quad partials to small ylds, intra-wave flush every 8 steps (no barriers). ----
__global__ __launch_bounds__(256) void k6_scanC(
    const float* __restrict__ gdelta, const float* __restrict__ x,
    const float* __restrict__ gB, const float* __restrict__ gC,
    const float* __restrict__ zb,
    const float* __restrict__ Alog, const float* __restrict__ AlogB,
    const float* __restrict__ Dvec, const float* __restrict__ DvecB,
    const float* __restrict__ hstart,
    float* __restrict__ y, float* __restrict__ yb) {
  __shared__ float sdl[64 * SROW];
  __shared__ float sx[64 * SROW];
  __shared__ float sB[CT * BROW];
  __shared__ float sC[CT * BROW];
  __shared__ float ylds[64 * 36];   // [d][tb*4 + sub], stride 36 (2-way max)
  __shared__ float sD[64];
  const int s = blockIdx.x;
  const int d0 = blockIdx.y * 64;
  const int dir = blockIdx.z >> 2, b = blockIdx.z & 3;
  const int t0 = s * CT;
  const int tid = threadIdx.x;
  const size_t ob = (size_t)dir * BN + b;

  {
    const int q = tid & 7, r2 = tid >> 3;
#pragma unroll
    for (int p = 0; p < 2; ++p) {
      int row = r2 + p * 32;
      f32x4 dl = *(const f32x4*)(gdelta + (ob * DD + d0 + row) * LL + t0 + q * 4);
      f32x4 xv;
      if (dir == 0) {
        xv = *(const f32x4*)(x + ((size_t)b * DD + d0 + row) * LL + t0 + q * 4);
      } else {
        f32x4 t = *(const f32x4*)(x + ((size_t)b * DD + d0 + row) * LL + (LL - 4 - t0 - q * 4));
        xv = (f32x4){t[3], t[2], t[1], t[0]};
      }
      *(f32x4*)&sdl[row * SROW + q * 4] = dl;
      *(f32x4*)&sx[row * SROW + q * 4] = xv;
    }
    const int t = tid & 31, n8 = tid >> 5;
#pragma unroll
    for (int p = 0; p < 2; ++p) {
      int n = n8 + p * 8;
      sB[t * BROW + n] = gB[(ob * NS + n) * LL + t0 + t];
      sC[t * BROW + n] = gC[(ob * NS + n) * LL + t0 + t];
    }
    if (tid < 64) sD[tid] = (dir ? DvecB : Dvec)[d0 + tid];
  }
  __syncthreads();

  const int dq = tid >> 2, sub = tid & 3, n0 = sub * 4;
  const int lane = tid & 63, w = tid >> 6;
  const int d = d0 + dq;
  f32x4 Al = *(const f32x4*)((dir ? AlogB : Alog) + d * NS + n0);
  f32x4 An2;
  An2[0] = -__expf(Al[0]) * LOG2E;
  An2[1] = -__expf(Al[1]) * LOG2E;
  An2[2] = -__expf(Al[2]) * LOG2E;
  An2[3] = -__expf(Al[3]) * LOG2E;

  const size_t pidx = ((ob * DD + d) * (size_t)NCH + s) * NS + n0;
  f32x4 h = *(const f32x4*)(hstart + pidx);

  const float* zbase = zb + ((size_t)b * DD + d0) * LL + t0;
  float* dbase = (dir ? yb : y) + ((size_t)b * DD + d0) * LL + t0;
  const int dql = lane >> 3, tql = lane & 7;   // flush mapping (intra-wave)

  for (int jb = 0; jb < CT; jb += 8) {
#pragma unroll
    for (int j2 = 0; j2 < 8; j2 += 4) {
      f32x4 dl4 = *(const f32x4*)&sdl[dq * SROW + jb + j2];
      f32x4 x4  = *(const f32x4*)&sx[dq * SROW + jb + j2];
#pragma unroll
      for (int q = 0; q < 4; ++q) {
        int t = jb + j2 + q;
        f32x4 Bv = *(const f32x4*)&sB[t * BROW + n0];
        f32x4 Cv = *(const f32x4*)&sC[t * BROW + n0];
        float dl = dl4[q];
        float dlx = dl * x4[q];
        f32x4 e = exp2v(dl * An2);
        h = h * e + dlx * Bv;
        f32x4 yc = h * Cv;
        ylds[dq * 36 + ((j2 + q) << 2) + sub] = (yc[0] + yc[1]) + (yc[2] + yc[3]);
      }
    }
    // flush: wave w covers d = w*16..w*16+15; reads only its own writes (in-order DS)
#pragma unroll
    for (int k = 0; k < 2; ++k) {
      int dd = w * 16 + dql + 8 * k;
      int tt = jb + tql;
      f32x4 pv = *(const f32x4*)&ylds[dd * 36 + tql * 4];
      float sum = (pv[0] + pv[1]) + (pv[2] + pv[3]);
      float xv = sx[dd * SROW + tt];
      float zv = zbase[(size_t)dd * LL + tt];
      dbase[(size_t)dd * LL + tt] = (sum + sD[dd] * xv) * silu_f(zv);
    }
  }
}

// ---------------- K7: dual LayerNorm + double SiLU gate + flip-add ----------------
__global__ __launch_bounds__(256) void k7_final(
    const float* __restrict__ y, const float* __restrict__ yb,
    const float* __restrict__ zb,
    const float* __restrict__ lnw, const float* __restrict__ lnb,
    const float* __restrict__ ln1w, const float* __restrict__ ln1b,
    float* __restrict__ out) {
  __shared__ float sy[LL];
  __shared__ float syb[LL];
  __shared__ float rsum[4][4];
  const int row = blockIdx.x;
  const int tid = threadIdx.x;
  const size_t base = (size_t)row * LL;
  float s1y = 0.f, s2y = 0.f, s1b = 0.f, s2b = 0.f;
  for (int j = tid * 4; j < LL; j += 1024) {
    float4 v = *(const float4*)(y + base + j);
    *(float4*)&sy[j] = v;
    s1y += v.x + v.y + v.z + v.w;
    s2y += v.x * v.x + v.y * v.y + v.z * v.z + v.w * v.w;
    float4 w = *(const float4*)(yb + base + j);
    *(float4*)&syb[j] = w;
    s1b += w.x + w.y + w.z + w.w;
    s2b += w.x * w.x + w.y * w.y + w.z * w.z + w.w * w.w;
  }
#pragma unroll
  for (int m = 1; m < 64; m <<= 1) {
    s1y += __shfl_xor(s1y, m); s2y += __shfl_xor(s2y, m);
    s1b += __shfl_xor(s1b, m); s2b += __shfl_xor(s2b, m);
  }
  int wv = tid >> 6;
  if ((tid & 63) == 0) { rsum[wv][0] = s1y; rsum[wv][1] = s2y; rsum[wv][2] = s1b; rsum[wv][3] = s2b; }
  __syncthreads();
  float t1y = rsum[0][0] + rsum[1][0] + rsum[2][0] + rsum[3][0];
  float t2y = rsum[0][1] + rsum[1][1] + rsum[2][1] + rsum[3][1];
  float t1b = rsum[0][2] + rsum[1][2] + rsum[2][2] + rsum[3][2];
  float t2b = rsum[0][3] + rsum[1][3] + rsum[2][3] + rsum[3][3];
  const float inv = 1.f / (float)LL;
  float mY = t1y * inv; float vY = t2y * inv - mY * mY; float rY = rsqrtf(vY + 1e-5f);
  float mB = t1b * inv; float vB = t2b * inv - mB * mB; float rB = rsqrtf(vB + 1e-5f);
  for (int j = tid; j < LL; j += 256) {
    int jr = LL - 1 - j;
    float a  = (sy[j]  - mY) * rY * lnw[j]   + lnb[j];
    float g1 = silu_f(zb[base + j]);
    float bv = (syb[jr] - mB) * rB * ln1w[jr] + ln1b[jr];
    float g2 = silu_f(zb[base + jr]);
    out[base + j] = a * g1 + bv * g2;
  }
}

extern "C" void kernel_launch(void* const* d_in, const int* in_sizes, int n_in,
                              void* d_out, int out_size, void* d_ws, size_t ws_size,
                              hipStream_t stream) {
  const float* u     = (const float*)d_in[0];
  const float* inw   = (const float*)d_in[1];
  const float* cw    = (const float*)d_in[2];
  const float* cb    = (const float*)d_in[3];
  const float* xpw   = (const float*)d_in[4];
  const float* dtw   = (const float*)d_in[5];
  const float* dtb   = (const float*)d_in[6];
  const float* Alog  = (const float*)d_in[7];
  const float* Dv    = (const float*)d_in[8];
  const float* xpwB  = (const float*)d_in[9];
  const float* dtwB  = (const float*)d_in[10];
  const float* AlogB = (const float*)d_in[11];
  const float* DvB   = (const float*)d_in[12];
  const float* lnw   = (const float*)d_in[13];
  const float* lnb   = (const float*)d_in[14];
  const float* ln1w  = (const float*)d_in[15];
  const float* ln1b  = (const float*)d_in[16];
  float* out = (float*)d_out;

  float* ws = (float*)d_ws;
  const size_t SZ = (size_t)BN * DD * LL;        // 4,194,304 floats
  float* xpre   = ws;
  float* zb     = ws + SZ;
  float* xc     = ws + 2 * SZ;
  float* gdelta = ws + 3 * SZ;        // 2 dirs
  float* gB     = ws + 5 * SZ;
  float* gC     = gB + SZ / 8;
  float* Pbuf   = gC + SZ / 8;        // 2*4*256*128*16 = SZ floats (NCH=128)
  float* qbuf   = Pbuf + SZ;          // becomes hstart after k5_mid; total 7.25*SZ
  float* ybuf   = xpre;               // alias: xpre dead after k2
  float* ybbuf  = Pbuf;               // alias: Pbuf only read by k5, dead before k6 writes
  float* dtr    = Pbuf;               // alias: dtr dead (after k3b) before k4 writes Pbuf

  k1_mfma<<<dim3(64, 4, 4), 256, 0, stream>>>(inw, u, xpre, zb);
  k2_conv<<<1024, 256, 0, stream>>>(xpre, cw, cb, xc);
  k3_xproj<<<dim3(16, 4, 16), 256, 0, stream>>>(xc, xpw, xpwB, dtr, gB, gC);
  k3b_dtproj<<<dim3(16, 8, 16), 256, 0, stream>>>(dtr, dtw, dtwB, dtb, gdelta);
  k4_scanA<<<dim3(NCH - 1, 4, 8), 256, 0, stream>>>(gdelta, xc, gB, Alog, AlogB, Pbuf, qbuf);
  k5_mid<<<512, 64, 0, stream>>>(Pbuf, qbuf);
  k6_scanC<<<dim3(NCH, 4, 8), 256, 0, stream>>>(gdelta, xc, gB, gC, zb, Alog, AlogB,
                                                Dv, DvB, qbuf, ybuf, ybbuf);
  k7_final<<<1024, 256, 0, stream>>>(ybuf, ybbuf, zb, lnw, lnb, ln1w, ln1b, out);
}